// Round 1
// baseline (220.855 us; speedup 1.0000x reference)
//
#include <hip/hip_runtime.h>

#define MARGIN_NEG 0.4f
#define MARGIN_POS 0.01f

// Problem constants: B=64, C=3, H=W=256 -> N = 12,582,912 elems; z: 64 x 16384
#define N_ELEM   12582912
#define N4       (N_ELEM / 4)          // 3,145,728 float4 per tensor
#define BATCH    64
#define DIMZ     16384
#define ROW4     (DIMZ / 4)            // 4096 float4 per z-row

typedef float vf4 __attribute__((ext_vector_type(4)));

// MSE: 3072 blocks; each block owns a contiguous 16-KB window (1024 float4)
// of each of the 4 streams. Each thread issues ALL 16 of its loads in one
// batch (256 B in flight), computes, reduces, exits.
// R1 change: PLAIN loads (no nontemporal hint). The full 209 MB input set
// fits in the 256 MiB Infinity Cache; nt was marking lines evict-first and
// discarding cross-iteration L3 residency (FETCH_SIZE showed only half the
// logical traffic hitting L3). Let the cache do its job.
#define MSE_BLKS  3072
#define F4_PER_STREAM_BLK 1024         // N4 / MSE_BLKS
#define CB        1024                 // contrastive blocks (last in grid)

// ws layout (floats), all plain stores, every slot written exactly once:
//   [kc*4096 + m*64 + n], kc in 0..3 : contrastive partial d sums   (16384)
//   [16384 + mseBlock]               : per-block MSE partials       (3072)
#define MSE_OFF  16384

__global__ __launch_bounds__(256) void fused_pass1(
        const float* __restrict__ o1, const float* __restrict__ i1,
        const float* __restrict__ o2, const float* __restrict__ i2,
        const float* __restrict__ z1, const float* __restrict__ z2,
        float* __restrict__ ws) {
    const int b = blockIdx.x;
    const int t = threadIdx.x;
    const int lane = t & 63, wid = t >> 6;

    if (b < MSE_BLKS) {
        // ------- MSE: single-batch streaming, max block churn -------
        const vf4* A1 = (const vf4*)o1;
        const vf4* B1 = (const vf4*)i1;
        const vf4* A2 = (const vf4*)o2;
        const vf4* B2 = (const vf4*)i2;
        const int base = b * F4_PER_STREAM_BLK + t;   // stream-local f4 index

        vf4 a1[4], a2[4], b1[4], b2[4];
        // Grouped by stream: same-offset A/B pairs separated in issue order.
        #pragma unroll
        for (int j = 0; j < 4; j++) a1[j] = A1[base + j * 256];
        #pragma unroll
        for (int j = 0; j < 4; j++) a2[j] = A2[base + j * 256];
        #pragma unroll
        for (int j = 0; j < 4; j++) b1[j] = B1[base + j * 256];
        #pragma unroll
        for (int j = 0; j < 4; j++) b2[j] = B2[base + j * 256];

        float acc0 = 0.f, acc1 = 0.f, acc2 = 0.f, acc3 = 0.f;
        #pragma unroll
        for (int j = 0; j < 4; j++) {
            vf4 d1 = a1[j] - b1[j];
            vf4 d2 = a2[j] - b2[j];
            acc0 += d1.x * d1.x + d1.y * d1.y;
            acc1 += d1.z * d1.z + d1.w * d1.w;
            acc2 += d2.x * d2.x + d2.y * d2.y;
            acc3 += d2.z * d2.z + d2.w * d2.w;
        }
        float v = (acc0 + acc1) + (acc2 + acc3);
        #pragma unroll
        for (int off = 32; off > 0; off >>= 1) v += __shfl_down(v, off, 64);
        __shared__ float ws4[4];
        if (lane == 0) ws4[wid] = v;
        __syncthreads();
        if (t == 0) ws[MSE_OFF + b] = ws4[0] + ws4[1] + ws4[2] + ws4[3];
    } else {
        // ---- contrastive: partial sums of sum_k (z1[m,k]-z2[n,k])^2, k-split x4 ----
        const int cb   = b - MSE_BLKS;
        const int kc   = cb & 3;            // k-chunk: 1024 float4 = 4096 floats
        const int tile = cb >> 2;           // 0..255
        const int m0 = (tile >> 4) * 4;
        const int n0 = (tile & 15) * 4;
        const float4* z1v = (const float4*)z1;
        const float4* z2v = (const float4*)z2;

        float acc[16];
        #pragma unroll
        for (int p = 0; p < 16; p++) acc[p] = 0.f;

        const int cbase = kc * 1024 + t;
        #pragma unroll
        for (int it = 0; it < 4; it++) {
            const int c = cbase + it * 256;
            float4 a[4], bz[4];
            #pragma unroll
            for (int i = 0; i < 4; i++) a[i] = z1v[(m0 + i) * ROW4 + c];
            #pragma unroll
            for (int j = 0; j < 4; j++) bz[j] = z2v[(n0 + j) * ROW4 + c];
            #pragma unroll
            for (int i = 0; i < 4; i++) {
                #pragma unroll
                for (int j = 0; j < 4; j++) {
                    float dx = a[i].x - bz[j].x, dy = a[i].y - bz[j].y;
                    float dz = a[i].z - bz[j].z, dw = a[i].w - bz[j].w;
                    acc[i * 4 + j] += dx * dx + dy * dy + dz * dz + dw * dw;
                }
            }
        }

        __shared__ float wsum[4][16];
        #pragma unroll
        for (int p = 0; p < 16; p++) {
            float v = acc[p];
            #pragma unroll
            for (int off = 32; off > 0; off >>= 1) v += __shfl_down(v, off, 64);
            if (lane == 0) wsum[wid][p] = v;
        }
        __syncthreads();
        if (t < 16) {
            float s = wsum[0][t] + wsum[1][t] + wsum[2][t] + wsum[3][t];
            int m = m0 + (t >> 2), n = n0 + (t & 3);
            ws[kc * 4096 + m * 64 + n] = s;   // plain store, unique slot
        }
    }
}

// Reduce partials + margins + finalize: one block of 256 threads.
__global__ __launch_bounds__(256) void fused_pass2(const float* __restrict__ ws,
                                                   float* __restrict__ out) {
    const int t = threadIdx.x;
    const int lane = t & 63, wid = t >> 6;

    float msum = 0.f;
    #pragma unroll
    for (int s = 0; s < 12; s++) msum += ws[MSE_OFF + t + s * 256];  // 3072 partials

    float p = 0.f, q = 0.f;
    #pragma unroll
    for (int s = 0; s < 16; s++) {
        int idx = t + s * 256;                                       // 4096 pairs
        float d = (ws[idx] + ws[4096 + idx] + ws[8192 + idx] + ws[12288 + idx])
                  * (1.0f / (float)DIMZ);
        int m = idx >> 6, n = idx & 63;
        if (m == n) { if (d > MARGIN_POS) p += d - MARGIN_POS; }
        else        { if (d < MARGIN_NEG) q += MARGIN_NEG - d; }
    }

    #pragma unroll
    for (int off = 32; off > 0; off >>= 1) {
        msum += __shfl_down(msum, off, 64);
        p    += __shfl_down(p,    off, 64);
        q    += __shfl_down(q,    off, 64);
    }
    __shared__ float sm[4], sp[4], sq[4];
    if (lane == 0) { sm[wid] = msum; sp[wid] = p; sq[wid] = q; }
    __syncthreads();
    if (t == 0) {
        float M = sm[0] + sm[1] + sm[2] + sm[3];
        float P = sp[0] + sp[1] + sp[2] + sp[3];
        float Q = sq[0] + sq[1] + sq[2] + sq[3];
        out[0] = M * (1.0f / (float)N_ELEM)
               + 1.5f * (P / (float)BATCH)
               + 0.5f * (Q / (float)(BATCH * (BATCH - 1)));
    }
}

extern "C" void kernel_launch(void* const* d_in, const int* in_sizes, int n_in,
                              void* d_out, int out_size, void* d_ws, size_t ws_size,
                              hipStream_t stream) {
    const float* outputs1 = (const float*)d_in[0];
    const float* z1       = (const float*)d_in[1];
    const float* outputs2 = (const float*)d_in[2];
    const float* z2       = (const float*)d_in[3];
    const float* input1   = (const float*)d_in[4];
    const float* input2   = (const float*)d_in[5];
    float* out = (float*)d_out;
    float* ws  = (float*)d_ws;

    fused_pass1<<<MSE_BLKS + CB, 256, 0, stream>>>(outputs1, input1, outputs2, input2,
                                                   z1, z2, ws);
    fused_pass2<<<1, 256, 0, stream>>>(ws, out);
}

// Round 2
// 200.592 us; speedup vs baseline: 1.1010x; 1.1010x over previous
//
#include <hip/hip_runtime.h>

#define MARGIN_NEG 0.4f
#define MARGIN_POS 0.01f

// Problem constants: B=64, C=3, H=W=256 -> N = 12,582,912 elems; z: 64 x 16384
#define N_ELEM   12582912
#define N4       (N_ELEM / 4)          // 3,145,728 float4 per tensor
#define BATCH    64
#define DIMZ     16384
#define ROW4     (DIMZ / 4)            // 4096 float4 per z-row

// Native clang vector type: required by __builtin_nontemporal_load.
typedef float vf4 __attribute__((ext_vector_type(4)));

// R2: nt loads REVERTED IN (R1 proved plain loads ~1.8x slower at identical
// FETCH_SIZE -- nt's L1 bypass is the fast path; L3 hit fraction is set by
// the harness restore writes, not load policy).
// New lever: 2x per-wave MLP. 1536 MSE blocks, each owns a 32-KB window
// (2048 float4) of each stream; every thread issues ALL 32 of its nt loads
// (512 B/lane in flight) in one batch, then consumes. Tests queue-depth-bound
// (H1: BW rises) vs shared-fabric-path-bound (H2: no change).
#define MSE_BLKS  1536
#define F4_PER_STREAM_BLK 2048         // N4 / MSE_BLKS
#define CB        1024                 // contrastive blocks (last in grid)

// ws layout (floats), all plain stores, every slot written exactly once:
//   [kc*4096 + m*64 + n], kc in 0..3 : contrastive partial d sums   (16384)
//   [16384 + mseBlock]               : per-block MSE partials       (1536)
#define MSE_OFF  16384

__global__ __launch_bounds__(256) void fused_pass1(
        const float* __restrict__ o1, const float* __restrict__ i1,
        const float* __restrict__ o2, const float* __restrict__ i2,
        const float* __restrict__ z1, const float* __restrict__ z2,
        float* __restrict__ ws) {
    const int b = blockIdx.x;
    const int t = threadIdx.x;
    const int lane = t & 63, wid = t >> 6;

    if (b < MSE_BLKS) {
        // ------- MSE: single-batch nt streaming, 32 loads in flight -------
        const vf4* A1 = (const vf4*)o1;
        const vf4* B1 = (const vf4*)i1;
        const vf4* A2 = (const vf4*)o2;
        const vf4* B2 = (const vf4*)i2;
        const int base = b * F4_PER_STREAM_BLK + t;   // stream-local f4 index

        vf4 a1[8], a2[8], b1[8], b2[8];
        // Grouped by stream: same-offset A/B pairs separated in issue order.
        #pragma unroll
        for (int j = 0; j < 8; j++) a1[j] = __builtin_nontemporal_load(&A1[base + j * 256]);
        #pragma unroll
        for (int j = 0; j < 8; j++) a2[j] = __builtin_nontemporal_load(&A2[base + j * 256]);
        #pragma unroll
        for (int j = 0; j < 8; j++) b1[j] = __builtin_nontemporal_load(&B1[base + j * 256]);
        #pragma unroll
        for (int j = 0; j < 8; j++) b2[j] = __builtin_nontemporal_load(&B2[base + j * 256]);

        float acc0 = 0.f, acc1 = 0.f, acc2 = 0.f, acc3 = 0.f;
        #pragma unroll
        for (int j = 0; j < 8; j++) {
            vf4 d1 = a1[j] - b1[j];
            vf4 d2 = a2[j] - b2[j];
            acc0 += d1.x * d1.x + d1.y * d1.y;
            acc1 += d1.z * d1.z + d1.w * d1.w;
            acc2 += d2.x * d2.x + d2.y * d2.y;
            acc3 += d2.z * d2.z + d2.w * d2.w;
        }
        float v = (acc0 + acc1) + (acc2 + acc3);
        #pragma unroll
        for (int off = 32; off > 0; off >>= 1) v += __shfl_down(v, off, 64);
        __shared__ float ws4[4];
        if (lane == 0) ws4[wid] = v;
        __syncthreads();
        if (t == 0) ws[MSE_OFF + b] = ws4[0] + ws4[1] + ws4[2] + ws4[3];
    } else {
        // ---- contrastive: partial sums of sum_k (z1[m,k]-z2[n,k])^2, k-split x4 ----
        const int cb   = b - MSE_BLKS;
        const int kc   = cb & 3;            // k-chunk: 1024 float4 = 4096 floats
        const int tile = cb >> 2;           // 0..255
        const int m0 = (tile >> 4) * 4;
        const int n0 = (tile & 15) * 4;
        const float4* z1v = (const float4*)z1;
        const float4* z2v = (const float4*)z2;

        float acc[16];
        #pragma unroll
        for (int p = 0; p < 16; p++) acc[p] = 0.f;

        const int cbase = kc * 1024 + t;
        #pragma unroll
        for (int it = 0; it < 4; it++) {
            const int c = cbase + it * 256;
            float4 a[4], bz[4];
            #pragma unroll
            for (int i = 0; i < 4; i++) a[i] = z1v[(m0 + i) * ROW4 + c];
            #pragma unroll
            for (int j = 0; j < 4; j++) bz[j] = z2v[(n0 + j) * ROW4 + c];
            #pragma unroll
            for (int i = 0; i < 4; i++) {
                #pragma unroll
                for (int j = 0; j < 4; j++) {
                    float dx = a[i].x - bz[j].x, dy = a[i].y - bz[j].y;
                    float dz = a[i].z - bz[j].z, dw = a[i].w - bz[j].w;
                    acc[i * 4 + j] += dx * dx + dy * dy + dz * dz + dw * dw;
                }
            }
        }

        __shared__ float wsum[4][16];
        #pragma unroll
        for (int p = 0; p < 16; p++) {
            float v = acc[p];
            #pragma unroll
            for (int off = 32; off > 0; off >>= 1) v += __shfl_down(v, off, 64);
            if (lane == 0) wsum[wid][p] = v;
        }
        __syncthreads();
        if (t < 16) {
            float s = wsum[0][t] + wsum[1][t] + wsum[2][t] + wsum[3][t];
            int m = m0 + (t >> 2), n = n0 + (t & 3);
            ws[kc * 4096 + m * 64 + n] = s;   // plain store, unique slot
        }
    }
}

// Reduce partials + margins + finalize: one block of 256 threads.
__global__ __launch_bounds__(256) void fused_pass2(const float* __restrict__ ws,
                                                   float* __restrict__ out) {
    const int t = threadIdx.x;
    const int lane = t & 63, wid = t >> 6;

    float msum = 0.f;
    #pragma unroll
    for (int s = 0; s < 6; s++) msum += ws[MSE_OFF + t + s * 256];  // 1536 partials

    float p = 0.f, q = 0.f;
    #pragma unroll
    for (int s = 0; s < 16; s++) {
        int idx = t + s * 256;                                       // 4096 pairs
        float d = (ws[idx] + ws[4096 + idx] + ws[8192 + idx] + ws[12288 + idx])
                  * (1.0f / (float)DIMZ);
        int m = idx >> 6, n = idx & 63;
        if (m == n) { if (d > MARGIN_POS) p += d - MARGIN_POS; }
        else        { if (d < MARGIN_NEG) q += MARGIN_NEG - d; }
    }

    #pragma unroll
    for (int off = 32; off > 0; off >>= 1) {
        msum += __shfl_down(msum, off, 64);
        p    += __shfl_down(p,    off, 64);
        q    += __shfl_down(q,    off, 64);
    }
    __shared__ float sm[4], sp[4], sq[4];
    if (lane == 0) { sm[wid] = msum; sp[wid] = p; sq[wid] = q; }
    __syncthreads();
    if (t == 0) {
        float M = sm[0] + sm[1] + sm[2] + sm[3];
        float P = sp[0] + sp[1] + sp[2] + sp[3];
        float Q = sq[0] + sq[1] + sq[2] + sq[3];
        out[0] = M * (1.0f / (float)N_ELEM)
               + 1.5f * (P / (float)BATCH)
               + 0.5f * (Q / (float)(BATCH * (BATCH - 1)));
    }
}

extern "C" void kernel_launch(void* const* d_in, const int* in_sizes, int n_in,
                              void* d_out, int out_size, void* d_ws, size_t ws_size,
                              hipStream_t stream) {
    const float* outputs1 = (const float*)d_in[0];
    const float* z1       = (const float*)d_in[1];
    const float* outputs2 = (const float*)d_in[2];
    const float* z2       = (const float*)d_in[3];
    const float* input1   = (const float*)d_in[4];
    const float* input2   = (const float*)d_in[5];
    float* out = (float*)d_out;
    float* ws  = (float*)d_ws;

    fused_pass1<<<MSE_BLKS + CB, 256, 0, stream>>>(outputs1, input1, outputs2, input2,
                                                   z1, z2, ws);
    fused_pass2<<<1, 256, 0, stream>>>(ws, out);
}

// Round 3
// 198.621 us; speedup vs baseline: 1.1119x; 1.0099x over previous
//
#include <hip/hip_runtime.h>

#define MARGIN_NEG 0.4f
#define MARGIN_POS 0.01f

// Problem constants: B=64, C=3, H=W=256 -> N = 12,582,912 elems; z: 64 x 16384
#define N_ELEM   12582912
#define N4       (N_ELEM / 4)          // 3,145,728 float4 per tensor
#define BATCH    64
#define DIMZ     16384
#define ROW4     (DIMZ / 4)            // 4096 float4 per z-row

// Native clang vector type: required by __builtin_nontemporal_load.
typedef float vf4 __attribute__((ext_vector_type(4)));

// R3 changes (two low-risk levers; R2 proved MLP depth + block count null):
//  1. Contrastive blocks moved to the FRONT of the grid (b < CB). They
//     previously dispatched last and their z-read + reduce latency extended
//     the kernel past the MSE drain. Now they overlap MSE fully from t=0.
//  2. z-loads are nontemporal too: R1 proved the L1-allocating path is ~1.8x
//     slower per byte at identical FETCH_SIZE; z has no L1 reuse.
// MSE geometry unchanged from R2 (1536 blocks x 32-KB windows, 32 nt loads
// per thread in one batch -- measured identical to R0's 3072x16).
#define MSE_BLKS  1536
#define F4_PER_STREAM_BLK 2048         // N4 / MSE_BLKS
#define CB        1024                 // contrastive blocks (FIRST in grid)

// ws layout (floats), all plain stores, every slot written exactly once:
//   [kc*4096 + m*64 + n], kc in 0..3 : contrastive partial d sums   (16384)
//   [16384 + mseBlock]               : per-block MSE partials       (1536)
#define MSE_OFF  16384

__global__ __launch_bounds__(256) void fused_pass1(
        const float* __restrict__ o1, const float* __restrict__ i1,
        const float* __restrict__ o2, const float* __restrict__ i2,
        const float* __restrict__ z1, const float* __restrict__ z2,
        float* __restrict__ ws) {
    const int b = blockIdx.x;
    const int t = threadIdx.x;
    const int lane = t & 63, wid = t >> 6;

    if (b >= CB) {
        // ------- MSE: single-batch nt streaming, 32 loads in flight -------
        const int mb = b - CB;
        const vf4* A1 = (const vf4*)o1;
        const vf4* B1 = (const vf4*)i1;
        const vf4* A2 = (const vf4*)o2;
        const vf4* B2 = (const vf4*)i2;
        const int base = mb * F4_PER_STREAM_BLK + t;  // stream-local f4 index

        vf4 a1[8], a2[8], b1[8], b2[8];
        // Grouped by stream: same-offset A/B pairs separated in issue order.
        #pragma unroll
        for (int j = 0; j < 8; j++) a1[j] = __builtin_nontemporal_load(&A1[base + j * 256]);
        #pragma unroll
        for (int j = 0; j < 8; j++) a2[j] = __builtin_nontemporal_load(&A2[base + j * 256]);
        #pragma unroll
        for (int j = 0; j < 8; j++) b1[j] = __builtin_nontemporal_load(&B1[base + j * 256]);
        #pragma unroll
        for (int j = 0; j < 8; j++) b2[j] = __builtin_nontemporal_load(&B2[base + j * 256]);

        float acc0 = 0.f, acc1 = 0.f, acc2 = 0.f, acc3 = 0.f;
        #pragma unroll
        for (int j = 0; j < 8; j++) {
            vf4 d1 = a1[j] - b1[j];
            vf4 d2 = a2[j] - b2[j];
            acc0 += d1.x * d1.x + d1.y * d1.y;
            acc1 += d1.z * d1.z + d1.w * d1.w;
            acc2 += d2.x * d2.x + d2.y * d2.y;
            acc3 += d2.z * d2.z + d2.w * d2.w;
        }
        float v = (acc0 + acc1) + (acc2 + acc3);
        #pragma unroll
        for (int off = 32; off > 0; off >>= 1) v += __shfl_down(v, off, 64);
        __shared__ float ws4[4];
        if (lane == 0) ws4[wid] = v;
        __syncthreads();
        if (t == 0) ws[MSE_OFF + mb] = ws4[0] + ws4[1] + ws4[2] + ws4[3];
    } else {
        // ---- contrastive: partial sums of sum_k (z1[m,k]-z2[n,k])^2, k-split x4 ----
        const int cb   = b;
        const int kc   = cb & 3;            // k-chunk: 1024 float4 = 4096 floats
        const int tile = cb >> 2;           // 0..255
        const int m0 = (tile >> 4) * 4;
        const int n0 = (tile & 15) * 4;
        const vf4* z1v = (const vf4*)z1;
        const vf4* z2v = (const vf4*)z2;

        float acc[16];
        #pragma unroll
        for (int p = 0; p < 16; p++) acc[p] = 0.f;

        const int cbase = kc * 1024 + t;
        #pragma unroll
        for (int it = 0; it < 4; it++) {
            const int c = cbase + it * 256;
            vf4 a[4], bz[4];
            #pragma unroll
            for (int i = 0; i < 4; i++)
                a[i] = __builtin_nontemporal_load(&z1v[(m0 + i) * ROW4 + c]);
            #pragma unroll
            for (int j = 0; j < 4; j++)
                bz[j] = __builtin_nontemporal_load(&z2v[(n0 + j) * ROW4 + c]);
            #pragma unroll
            for (int i = 0; i < 4; i++) {
                #pragma unroll
                for (int j = 0; j < 4; j++) {
                    float dx = a[i].x - bz[j].x, dy = a[i].y - bz[j].y;
                    float dz = a[i].z - bz[j].z, dw = a[i].w - bz[j].w;
                    acc[i * 4 + j] += dx * dx + dy * dy + dz * dz + dw * dw;
                }
            }
        }

        __shared__ float wsum[4][16];
        #pragma unroll
        for (int p = 0; p < 16; p++) {
            float v = acc[p];
            #pragma unroll
            for (int off = 32; off > 0; off >>= 1) v += __shfl_down(v, off, 64);
            if (lane == 0) wsum[wid][p] = v;
        }
        __syncthreads();
        if (t < 16) {
            float s = wsum[0][t] + wsum[1][t] + wsum[2][t] + wsum[3][t];
            int m = m0 + (t >> 2), n = n0 + (t & 3);
            ws[kc * 4096 + m * 64 + n] = s;   // plain store, unique slot
        }
    }
}

// Reduce partials + margins + finalize: one block of 256 threads.
__global__ __launch_bounds__(256) void fused_pass2(const float* __restrict__ ws,
                                                   float* __restrict__ out) {
    const int t = threadIdx.x;
    const int lane = t & 63, wid = t >> 6;

    float msum = 0.f;
    #pragma unroll
    for (int s = 0; s < 6; s++) msum += ws[MSE_OFF + t + s * 256];  // 1536 partials

    float p = 0.f, q = 0.f;
    #pragma unroll
    for (int s = 0; s < 16; s++) {
        int idx = t + s * 256;                                       // 4096 pairs
        float d = (ws[idx] + ws[4096 + idx] + ws[8192 + idx] + ws[12288 + idx])
                  * (1.0f / (float)DIMZ);
        int m = idx >> 6, n = idx & 63;
        if (m == n) { if (d > MARGIN_POS) p += d - MARGIN_POS; }
        else        { if (d < MARGIN_NEG) q += MARGIN_NEG - d; }
    }

    #pragma unroll
    for (int off = 32; off > 0; off >>= 1) {
        msum += __shfl_down(msum, off, 64);
        p    += __shfl_down(p,    off, 64);
        q    += __shfl_down(q,    off, 64);
    }
    __shared__ float sm[4], sp[4], sq[4];
    if (lane == 0) { sm[wid] = msum; sp[wid] = p; sq[wid] = q; }
    __syncthreads();
    if (t == 0) {
        float M = sm[0] + sm[1] + sm[2] + sm[3];
        float P = sp[0] + sp[1] + sp[2] + sp[3];
        float Q = sq[0] + sq[1] + sq[2] + sq[3];
        out[0] = M * (1.0f / (float)N_ELEM)
               + 1.5f * (P / (float)BATCH)
               + 0.5f * (Q / (float)(BATCH * (BATCH - 1)));
    }
}

extern "C" void kernel_launch(void* const* d_in, const int* in_sizes, int n_in,
                              void* d_out, int out_size, void* d_ws, size_t ws_size,
                              hipStream_t stream) {
    const float* outputs1 = (const float*)d_in[0];
    const float* z1       = (const float*)d_in[1];
    const float* outputs2 = (const float*)d_in[2];
    const float* z2       = (const float*)d_in[3];
    const float* input1   = (const float*)d_in[4];
    const float* input2   = (const float*)d_in[5];
    float* out = (float*)d_out;
    float* ws  = (float*)d_ws;

    fused_pass1<<<MSE_BLKS + CB, 256, 0, stream>>>(outputs1, input1, outputs2, input2,
                                                   z1, z2, ws);
    fused_pass2<<<1, 256, 0, stream>>>(ws, out);
}